// Round 11
// baseline (17.843 us; speedup 1.0000x reference)
//
#include <hip/hip_runtime.h>
#include <math.h>

// Quanvolution via Pauli back-propagation (derivation R1, validated R1-R9):
//  alpha_q = theta_q + w0_q; A..D = cos(alpha_q), a..d = sin(alpha_q):
//   z0 = K0*A  + K1*ab
//   z1 = K2*B  + K3*A*bc + K4*ac
//   z2 = A*(K5*C + K7*bd) + K6*B*cd + a*(K8*bC + K9*d)          [factored]
//   z3 = B*(L1*D + L3*c) + A*(L2*Cd + L4*bcD + L5*b)
//      + a*(L6*bCd + L7*cD + L8)                                 [factored]
//
// R10 = R9 (best: 17.82) + factored monomials + 2-barrier tail.
//  256-thread block, 8 images; wave = (img-group g, K-half h); lane<49 owns
//  one horizontal patch-pair for 4 images; x = 2 aligned float4 per image;
//  W = 2 contiguous float4 per class, broadcast-reused by 4 images.
#define INV2PI 0.15915494309189535f

__device__ __forceinline__ float rfl(float v) {
    return __int_as_float(__builtin_amdgcn_readfirstlane(__float_as_int(v)));
}

__global__ __launch_bounds__(256, 4) void quanv_r10_kernel(
    const float* __restrict__ x,     // [B, 784]
    const float* __restrict__ wts,   // [2, 4]
    const float* __restrict__ W,     // [10, 784]
    const float* __restrict__ bias,  // [10]
    float* __restrict__ out,         // [B, 10]
    int B)
{
    __shared__ float part[4][8][40];   // [wave][octet][im*10+cl]
    __shared__ float logits[8][10];

    const int tid   = threadIdx.x;
    const int wave  = tid >> 6, lane = tid & 63;
    const int group = wave >> 1;          // image sub-set 0,1
    const int half  = wave & 1;           // pair-half 0,1
    const int imgb  = blockIdx.x * 8 + group * 4;

    // ---- pair geometry; issue x loads as early as possible ----
    const bool act = (lane < 49);
    const int q  = half * 49 + lane;      // pair 0..97
    const int pi = q / 7;                 // patch row 0..13
    const int pj = q - pi * 7;            // pair col 0..6
    const int xoff = pi * 56 + pj * 4;    // row 2pi, col 4pj (float4-aligned)

    float4 xt[4], xb[4];
#pragma unroll
    for (int im = 0; im < 4; ++im) {
        xt[im] = make_float4(0.f, 0.f, 0.f, 0.f);
        xb[im] = xt[im];
    }
    if (act) {
#pragma unroll
        for (int im = 0; im < 4; ++im) {
            const float* xp = x + (size_t)(imgb + im) * 784 + xoff;
            xt[im] = *(const float4*)xp;          // row 2pi
            xb[im] = *(const float4*)(xp + 28);   // row 2pi+1
        }
    }

    // ---- uniform constants, pinned to SGPRs (hides x latency) ----
    float w0r[4], cw1[4], sw1[4];
#pragma unroll
    for (int qq = 0; qq < 4; ++qq) {
        w0r[qq] = rfl(wts[qq] * INV2PI);
        float r = wts[4 + qq] * INV2PI;
        r -= floorf(r);
        cw1[qq] = __builtin_amdgcn_cosf(r);
        sw1[qq] = __builtin_amdgcn_sinf(r);
    }
    const float cc  = cw1[0]*cw1[1], cs = cw1[0]*sw1[1];
    const float sc  = sw1[0]*cw1[1], ss = sw1[0]*sw1[1];
    const float ccc = cc*cw1[2], ccs = cc*sw1[2], csc = cs*cw1[2], css = cs*sw1[2];
    const float scc = sc*cw1[2], ssc = ss*cw1[2], sss = ss*sw1[2];
    const float K0 = rfl(cw1[0]),       K1 = rfl(-sw1[0]);
    const float K2 = rfl(cc),           K3 = rfl(-cs),          K4 = rfl(ss);
    const float K5 = rfl(ccc),          K6 = rfl(-ccs),         K7 = rfl(css);
    const float K8 = rfl(-scc),         K9 = rfl(-sss);
    const float L1 = rfl(ccc*cw1[3]),   L2 = rfl(-ccc*sw1[3]);
    const float L3 = rfl(ccs*sw1[3]),   L4 = rfl(-csc*cw1[3]);
    const float L5 = rfl(-css*sw1[3]),  L6 = rfl(scc*sw1[3]);
    const float L7 = rfl(ssc*cw1[3]),   L8 = rfl(sss*sw1[3]);

    // ---- compute z for 4 images x 2 patches (factored forms) ----
    float z[4][2][4];
#pragma unroll
    for (int im = 0; im < 4; ++im) {
#pragma unroll
        for (int h2 = 0; h2 < 2; ++h2) {
            const float t0 = h2 ? xt[im].z : xt[im].x;
            const float t1 = h2 ? xt[im].w : xt[im].y;
            const float t2 = h2 ? xb[im].z : xb[im].x;
            const float t3 = h2 ? xb[im].w : xb[im].y;

            float r;
            r = fmaf(t0, INV2PI, w0r[0]); r -= floorf(r);
            const float a  = __builtin_amdgcn_sinf(r), A  = __builtin_amdgcn_cosf(r);
            r = fmaf(t1, INV2PI, w0r[1]); r -= floorf(r);
            const float b  = __builtin_amdgcn_sinf(r), Bv = __builtin_amdgcn_cosf(r);
            r = fmaf(t2, INV2PI, w0r[2]); r -= floorf(r);
            const float c  = __builtin_amdgcn_sinf(r), C  = __builtin_amdgcn_cosf(r);
            r = fmaf(t3, INV2PI, w0r[3]); r -= floorf(r);
            const float d  = __builtin_amdgcn_sinf(r), D  = __builtin_amdgcn_cosf(r);

            const float ab = a*b, bc = b*c, ac = a*c;
            const float bd = b*d, cd = c*d, bC = b*C;
            const float Cd = C*d, cD = c*D;
            const float bcD = b*cD, bCd = b*Cd, Bcd = Bv*cd;

            z[im][h2][0] = fmaf(K0, A, K1*ab);
            z[im][h2][1] = fmaf(K2, Bv, fmaf(K3, A*bc, K4*ac));
            // z2 = A*(K5*C + K7*bd) + K6*(B*cd) + a*(K8*bC + K9*d)
            const float t2a = fmaf(K5, C, K7*bd);
            const float t2b = fmaf(K8, bC, K9*d);
            z[im][h2][2] = fmaf(A, t2a, fmaf(K6, Bcd, a*t2b));
            // z3 = B*(L1*D + L3*c) + A*(L2*Cd + L4*bcD + L5*b) + a*(L6*bCd + L7*cD + L8)
            const float t3a = fmaf(L1, D, L3*c);
            const float t3b = fmaf(L2, Cd, fmaf(L4, bcD, L5*b));
            const float t3c = fmaf(L6, bCd, fmaf(L7, cD, L8));
            z[im][h2][3] = fmaf(Bv, t3a, fmaf(A, t3b, a*t3c));
        }
    }

    // ---- GEMM: 2 contiguous W float4 per class, reused by 4 images ----
    float acc[4][10];
#pragma unroll
    for (int im = 0; im < 4; ++im)
#pragma unroll
        for (int cl = 0; cl < 10; ++cl) acc[im][cl] = 0.f;

    if (act) {
        const int kL = pi * 56 + pj * 8;   // k-offset of patch (pi, 2pj)
#pragma unroll
        for (int cl = 0; cl < 10; ++cl) {
            const float* wp = W + cl * 784 + kL;
            const float4 wvL = *(const float4*)wp;
            const float4 wvR = *(const float4*)(wp + 4);
#pragma unroll
            for (int im = 0; im < 4; ++im)
                acc[im][cl] = fmaf(z[im][0][0], wvL.x, fmaf(z[im][0][1], wvL.y,
                              fmaf(z[im][0][2], wvL.z, fmaf(z[im][0][3], wvL.w,
                              fmaf(z[im][1][0], wvR.x, fmaf(z[im][1][1], wvR.y,
                              fmaf(z[im][1][2], wvR.z, fmaf(z[im][1][3], wvR.w,
                              acc[im][cl]))))))));
        }
    }

    // ---- 3-level butterfly within octets (DPP-cheap), octet sums to LDS ----
#pragma unroll
    for (int im = 0; im < 4; ++im)
#pragma unroll
        for (int cl = 0; cl < 10; ++cl) {
            float v = acc[im][cl];
            v += __shfl_xor(v, 1, 64);
            v += __shfl_xor(v, 2, 64);
            v += __shfl_xor(v, 4, 64);
            if ((lane & 7) == 0) part[wave][lane >> 3][im * 10 + cl] = v;
        }
    __syncthreads();

    // ---- logits: 80 threads, one (image, class) each ----
    if (tid < 80) {
        const int im8 = tid / 10, cl = tid - (tid / 10) * 10;
        const int g   = im8 >> 2;
        const int vv  = (im8 & 3) * 10 + cl;
        float s = bias[cl];
#pragma unroll
        for (int l = 0; l < 8; ++l)
            s += part[2 * g][l][vv] + part[2 * g + 1][l][vv];
        logits[im8][cl] = s;
    }
    __syncthreads();

    // ---- log_softmax + store: 80 threads, redundant per-image lse ----
    if (tid < 80) {
        const int im8 = tid / 10, cl = tid - (tid / 10) * 10;
        const int img = blockIdx.x * 8 + im8;
        if (img < B) {
            float m = logits[im8][0];
#pragma unroll
            for (int j = 1; j < 10; ++j) m = fmaxf(m, logits[im8][j]);
            float s = 0.f;
#pragma unroll
            for (int j = 0; j < 10; ++j) s += __expf(logits[im8][j] - m);
            out[(size_t)img * 10 + cl] = logits[im8][cl] - m - __logf(s);
        }
    }
}

extern "C" void kernel_launch(void* const* d_in, const int* in_sizes, int n_in,
                              void* d_out, int out_size, void* d_ws, size_t ws_size,
                              hipStream_t stream) {
    const float* x    = (const float*)d_in[0];
    const float* wts  = (const float*)d_in[1];
    const float* W    = (const float*)d_in[2];
    const float* bias = (const float*)d_in[3];
    float* out        = (float*)d_out;

    const int B = in_sizes[0] / 784;
    const int blocks = (B + 7) / 8;   // 8 images/block
    quanv_r10_kernel<<<blocks, 256, 0, stream>>>(x, wts, W, bias, out, B);
}